// Round 3
// baseline (1037.732 us; speedup 1.0000x reference)
//
#include <hip/hip_runtime.h>
#include <hip/hip_bf16.h>

// CommSlave fused kernel — Round 3: fp32 inputs AND fp32 outputs.
// Block = 256 threads = 32 rows = 4 attention groups (n_slave=8).
// Wave (64 lanes) = 8 rows x 8 lanes; lane owns 8 h-dims / 4 attn-dims of its row.

#define DIN   256
#define H     64
#define A_DIM 32
#define NACT  14
#define BROWS 32
#define BTOT  65536

__device__ __forceinline__ float sigm(float x){ return 1.0f / (1.0f + __expf(-x)); }
__device__ __forceinline__ float tanhp(float x){ return 1.0f - 2.0f / (__expf(2.0f * x) + 1.0f); }

__global__ __launch_bounds__(256, 3)
void commslave_f32(const float* __restrict__ obs,
                   const float* __restrict__ hid,
                   const float* __restrict__ encW,
                   const float* __restrict__ encb,
                   const float* __restrict__ Wih,
                   const float* __restrict__ Whh,
                   const float* __restrict__ bih,
                   const float* __restrict__ bhh,
                   const float* __restrict__ qW,
                   const float* __restrict__ kW,
                   const float* __restrict__ vW,
                   const float* __restrict__ vb,
                   const float* __restrict__ decW,
                   const float* __restrict__ decb,
                   float* __restrict__ out)
{
  // sA: obs fp32 (stride 260); later reused as attn area (stride 140: q@0,k@32,v@64,attn@96,xatt@104)
  __shared__ float sA[BROWS * 260];
  __shared__ float sH[BROWS * 68];   // hidden_in
  __shared__ float sX[BROWS * 68];   // x, then h_out

  const int tid = threadIdx.x;
  const int r   = tid >> 3;          // row in block (0..31)
  const int s   = tid & 7;           // slice within row
  const size_t rowbase = (size_t)blockIdx.x * BROWS;

  // ---- stage obs (32x256 f32) + hidden (32x64 f32) to LDS ----
  {
    const float4* ov = (const float4*)(obs + rowbase * DIN);
    #pragma unroll
    for (int i = 0; i < 8; i++) {
      int c = tid + i * 256;                 // 0..2047 chunks of 4 floats
      float4 w = ov[c];
      *(float4*)&sA[(c >> 6) * 260 + (c & 63) * 4] = w;
    }
    const float4* hv = (const float4*)(hid + rowbase * H);
    #pragma unroll
    for (int i = 0; i < 2; i++) {
      int c = tid + i * 256;                 // 0..511
      float4 w = hv[c];
      *(float4*)&sH[(c >> 4) * 68 + (c & 15) * 4] = w;
    }
  }
  __syncthreads();

  // ---- enc: x = relu(obs @ encW + encb); thread -> row r, cols 8s..8s+7 ----
  float acc[8];
  {
    float4 b0 = ((const float4*)encb)[2 * s];
    float4 b1 = ((const float4*)encb)[2 * s + 1];
    acc[0]=b0.x; acc[1]=b0.y; acc[2]=b0.z; acc[3]=b0.w;
    acc[4]=b1.x; acc[5]=b1.y; acc[6]=b1.z; acc[7]=b1.w;
    const float4* Wv = (const float4*)encW;  // [256][64] -> 16 float4/row
    const float* xr = &sA[r * 260];
    for (int k = 0; k < DIN; k++) {
      float xs = xr[k];
      float4 w0 = Wv[k * 16 + 2 * s];
      float4 w1 = Wv[k * 16 + 2 * s + 1];
      acc[0] += xs * w0.x; acc[1] += xs * w0.y; acc[2] += xs * w0.z; acc[3] += xs * w0.w;
      acc[4] += xs * w1.x; acc[5] += xs * w1.y; acc[6] += xs * w1.z; acc[7] += xs * w1.w;
    }
  }
  #pragma unroll
  for (int i = 0; i < 8; i++) sX[r * 68 + 8 * s + i] = fmaxf(acc[i], 0.0f);
  __syncthreads();

  // ---- GRU: gx = x@Wih^T + bih; gh = h@Whh^T + bhh; gate order r,z,n ----
  float xrow[64];
  #pragma unroll
  for (int i = 0; i < 16; i++) *(float4*)&xrow[4 * i] = *(const float4*)&sX[r * 68 + 4 * i];

  float accg[3][8];
  {
    const float4* Wv = (const float4*)Wih;   // [192][64] -> 16 float4/row
    for (int g = 0; g < 3; g++) {
      for (int jj = 0; jj < 8; jj++) {
        int wrow = g * 64 + 8 * s + jj;
        const float4* wp = &Wv[wrow * 16];
        float d = bih[wrow];
        #pragma unroll
        for (int c = 0; c < 16; c++) {
          float4 w = wp[c];
          d += xrow[4*c+0]*w.x + xrow[4*c+1]*w.y + xrow[4*c+2]*w.z + xrow[4*c+3]*w.w;
        }
        accg[g][jj] = d;
      }
    }
  }
  #pragma unroll
  for (int i = 0; i < 16; i++) *(float4*)&xrow[4 * i] = *(const float4*)&sH[r * 68 + 4 * i];
  float hn[8];
  {
    const float4* Wv = (const float4*)Whh;   // [192][64]
    for (int g = 0; g < 3; g++) {
      for (int jj = 0; jj < 8; jj++) {
        int wrow = g * 64 + 8 * s + jj;
        const float4* wp = &Wv[wrow * 16];
        float d = bhh[wrow];
        #pragma unroll
        for (int c = 0; c < 16; c++) {
          float4 w = wp[c];
          d += xrow[4*c+0]*w.x + xrow[4*c+1]*w.y + xrow[4*c+2]*w.z + xrow[4*c+3]*w.w;
        }
        if (g < 2) accg[g][jj] += d; else hn[jj] = d;
      }
    }
  }
  float hout[8];
  #pragma unroll
  for (int jj = 0; jj < 8; jj++) {
    float rr = sigm(accg[0][jj]);
    float zz = sigm(accg[1][jj]);
    float nn = tanhp(accg[2][jj] + rr * hn[jj]);
    float hp = sH[r * 68 + 8 * s + jj];
    hout[jj] = (1.0f - zz) * nn + zz * hp;
  }
  __syncthreads();                   // all reads of sX (x) done before overwrite
  #pragma unroll
  for (int jj = 0; jj < 8; jj++) sX[r * 68 + 8 * s + jj] = hout[jj];
  {
    // h_out to global (output 1), fp32, 32B per thread
    float4* hop = (float4*)(out + (size_t)BTOT * NACT);
    hop[(rowbase + r) * 16 + 2 * s]     = make_float4(hout[0], hout[1], hout[2], hout[3]);
    hop[(rowbase + r) * 16 + 2 * s + 1] = make_float4(hout[4], hout[5], hout[6], hout[7]);
  }
  __syncthreads();

  // ---- q,k,v: thread -> row r, attn dims 4s..4s+3 ----
  {
    float qa[4] = {0,0,0,0}, ka[4] = {0,0,0,0}, va[4];
    float4 bv = ((const float4*)vb)[s];
    va[0]=bv.x; va[1]=bv.y; va[2]=bv.z; va[3]=bv.w;
    const float4* qv = (const float4*)qW;    // [64][32] -> 8 float4/row, chunk s
    const float4* kv = (const float4*)kW;
    const float4* wv = (const float4*)vW;
    const float* hrow = &sX[r * 68];
    for (int k2 = 0; k2 < H; k2++) {
      float hx = hrow[k2];
      float4 wq = qv[k2 * 8 + s];
      float4 wk = kv[k2 * 8 + s];
      float4 ww = wv[k2 * 8 + s];
      qa[0] += hx * wq.x; qa[1] += hx * wq.y; qa[2] += hx * wq.z; qa[3] += hx * wq.w;
      ka[0] += hx * wk.x; ka[1] += hx * wk.y; ka[2] += hx * wk.z; ka[3] += hx * wk.w;
      va[0] += hx * ww.x; va[1] += hx * ww.y; va[2] += hx * ww.z; va[3] += hx * ww.w;
    }
    const float qs = 0.17677669529663687f;   // 1/sqrt(32) folded into q
    float* arow = &sA[r * 140];
    *(float4*)&arow[4 * s]      = make_float4(qa[0]*qs, qa[1]*qs, qa[2]*qs, qa[3]*qs);
    *(float4*)&arow[32 + 4 * s] = make_float4(ka[0], ka[1], ka[2], ka[3]);
    *(float4*)&arow[64 + 4 * s] = make_float4(fmaxf(va[0],0.f), fmaxf(va[1],0.f),
                                              fmaxf(va[2],0.f), fmaxf(va[3],0.f));
  }
  __syncthreads();

  // ---- attention: group = 8 consecutive rows (one wave); lane s scores vs row j=s ----
  const int gbase = r & ~7;
  const int ri    = r & 7;
  {
    const float* qrow = &sA[r * 140];
    const float* krow = &sA[(gbase + s) * 140 + 32];
    float sc = 0.f;
    #pragma unroll
    for (int a4 = 0; a4 < 32; a4 += 4) {
      float4 q4 = *(const float4*)&qrow[a4];
      float4 k4 = *(const float4*)&krow[a4];
      sc += q4.x*k4.x + q4.y*k4.y + q4.z*k4.z + q4.w*k4.w;
    }
    float m = (s == ri) ? -1e30f : sc;
    #pragma unroll
    for (int off = 1; off < 8; off <<= 1) m = fmaxf(m, __shfl_xor(m, off, 8));
    float p = (s == ri) ? 0.f : __expf(sc - m);
    float sum = p;
    #pragma unroll
    for (int off = 1; off < 8; off <<= 1) sum += __shfl_xor(sum, off, 8);
    sA[r * 140 + 96 + s] = p / sum;
  }
  __syncthreads();

  // ---- xatt[r][4s..4s+3] = sum_j attn[r][j] * v[j][:] ----
  {
    float xa[4] = {0,0,0,0};
    const float* at = &sA[r * 140 + 96];
    #pragma unroll
    for (int j = 0; j < 8; j++) {
      float aj = at[j];
      float4 v4 = *(const float4*)&sA[(gbase + j) * 140 + 64 + 4 * s];
      xa[0] += aj * v4.x; xa[1] += aj * v4.y; xa[2] += aj * v4.z; xa[3] += aj * v4.w;
    }
    *(float4*)&sA[r * 140 + 104 + 4 * s] = make_float4(xa[0], xa[1], xa[2], xa[3]);
  }
  __syncthreads();

  // ---- dec: out[row][c] = [h_out, xatt] @ decW + decb; lane s -> cols s and s+8 ----
  {
    const float* hrow  = &sX[r * 68];
    const float* xrow2 = &sA[r * 140 + 104];
    float o1 = decb[s];
    float o2 = (s < 6) ? decb[s + 8] : 0.f;
    for (int k2 = 0; k2 < H; k2++) {
      float hx = hrow[k2];
      o1 += hx * decW[k2 * NACT + s];
      if (s < 6) o2 += hx * decW[k2 * NACT + s + 8];
    }
    for (int a = 0; a < A_DIM; a++) {
      float hx = xrow2[a];
      o1 += hx * decW[(H + a) * NACT + s];
      if (s < 6) o2 += hx * decW[(H + a) * NACT + s + 8];
    }
    size_t orow = (rowbase + r) * NACT;
    out[orow + s] = o1;
    if (s < 6) out[orow + s + 8] = o2;
  }
}

extern "C" void kernel_launch(void* const* d_in, const int* in_sizes, int n_in,
                              void* d_out, int out_size, void* d_ws, size_t ws_size,
                              hipStream_t stream) {
  (void)in_sizes; (void)n_in; (void)d_ws; (void)ws_size; (void)out_size;
  const float* obs  = (const float*)d_in[0];
  const float* hid  = (const float*)d_in[1];
  const float* encW = (const float*)d_in[2];
  const float* encb = (const float*)d_in[3];
  const float* Wih  = (const float*)d_in[4];
  const float* Whh  = (const float*)d_in[5];
  const float* bih  = (const float*)d_in[6];
  const float* bhh  = (const float*)d_in[7];
  const float* qW   = (const float*)d_in[8];
  const float* kW   = (const float*)d_in[9];
  const float* vW   = (const float*)d_in[10];
  const float* vb   = (const float*)d_in[11];
  const float* decW = (const float*)d_in[12];
  const float* decb = (const float*)d_in[13];
  float* out = (float*)d_out;

  commslave_f32<<<BTOT / BROWS, 256, 0, stream>>>(
      obs, hid, encW, encb, Wih, Whh, bih, bhh, qW, kW, vW, vb, decW, decb, out);
}

// Round 4
// 155.944 us; speedup vs baseline: 6.6545x; 6.6545x over previous
//
#include <hip/hip_runtime.h>
#include <hip/hip_bf16.h>

// CommSlave fused MFMA kernel — Round 4.
// Block = 256 threads = 4 waves = 64 rows (8 attention groups). Grid = 1024.
// Wave w owns m-tile rows [16w,16w+16). All GEMMs via v_mfma_f32_16x16x32_bf16.
// Weights converted fp32->bf16 and staged in a phase-unioned 52 KB LDS buffer
// once per block (3 blocks/CU). Attention in fp32 VALU via LDS.
//
// Verified fragment mappings (learn_hip m89/m120):
//   A-frag: A[m=lane&15][k=(lane>>4)*8+j], 8 contiguous bf16 -> ds_read_b128
//   B-frag: B[k=(lane>>4)*8+j][n=lane&15]  (store B transposed: [n][k])
//   C/D   : col=lane&15, row=(lane>>4)*4+reg

#define DIN   256
#define H     64
#define A_DIM 32
#define NACT  14
#define MBLK  64
#define BTOT  65536

typedef unsigned int u32;
typedef unsigned short u16;
using short8 = __attribute__((ext_vector_type(8))) short;
using f32x4  = __attribute__((ext_vector_type(4))) float;

__device__ __forceinline__ u32 f2bf(float f){
  u32 x = __float_as_uint(f);
  return (x + 0x7fffu + ((x >> 16) & 1u)) >> 16;   // RNE
}
__device__ __forceinline__ float bf2f(u16 u){ return __uint_as_float(((u32)u) << 16); }
__device__ __forceinline__ u32 pk2(float a, float b){ return f2bf(a) | (f2bf(b) << 16); }
__device__ __forceinline__ float sigm(float x){ return 1.0f / (1.0f + __expf(-x)); }
__device__ __forceinline__ float tanhp(float x){ return 1.0f - 2.0f / (__expf(2.0f * x) + 1.0f); }

#define MFMA16(a,b,c) __builtin_amdgcn_mfma_f32_16x16x32_bf16((a),(b),(c),0,0,0)

// LDS map (ushort indices into ldsU[26624] = 53248 B):
//  R0 [0,17408): phase union —
//     enc : obsT half [64][136] @0 ; encWT half [64][136] @8704
//     gru : W (Wih then Whh) [192][72] @0
//     qkv : qkvT [96][72] @0 ; then attn fp32 [64 rows][104 f32] @f32-idx 0
//           decT [16][104] @us 13312 (= byte 26624, after attn fp32 area)
//  Cx [17408,22016): x [64][72] ; later xatt bf16 in cols 0..31
//  Dh [22016,26624): h_in [64][72] ; overwritten with h_out bf16

__global__ __launch_bounds__(256, 3)
void commslave_mfma(const float* __restrict__ obs,
                    const float* __restrict__ hid,
                    const float* __restrict__ encW,
                    const float* __restrict__ encb,
                    const float* __restrict__ Wih,
                    const float* __restrict__ Whh,
                    const float* __restrict__ bih,
                    const float* __restrict__ bhh,
                    const float* __restrict__ qW,
                    const float* __restrict__ kW,
                    const float* __restrict__ vW,
                    const float* __restrict__ vb,
                    const float* __restrict__ decW,
                    const float* __restrict__ decb,
                    float* __restrict__ out)
{
  __shared__ __align__(16) u16 ldsU[26624];
  float* R0f = (float*)ldsU;

  const int tid  = threadIdx.x;
  const int lane = tid & 63;
  const int w    = tid >> 6;
  const int quad = lane >> 4;
  const int l16  = lane & 15;
  const int M0   = 16 * w;
  const size_t rowbase = (size_t)blockIdx.x * MBLK;

  const float4* obs4 = (const float4*)(obs + rowbase * DIN);
  const float4* hid4 = (const float4*)hid;

  // ================= enc: x = relu(obs @ encW + encb), K=256 in 2 halves ====
  f32x4 ce[4];
  #pragma unroll
  for (int t = 0; t < 4; t++) ce[t] = (f32x4){0.f,0.f,0.f,0.f};

  #pragma unroll 1
  for (int half = 0; half < 2; half++) {
    if (half == 1) __syncthreads();        // retire half-0 frag reads
    // stage obsT half: [row 0..63][kk 0..127] bf16 @us 0, stride 136
    #pragma unroll
    for (int i = 0; i < 8; i++) {
      int idx = tid + 256 * i;             // 0..2047
      int row = idx >> 5, c4 = idx & 31;
      float4 v = obs4[row * 64 + half * 32 + c4];
      *(uint2*)&ldsU[row * 136 + c4 * 4] = make_uint2(pk2(v.x, v.y), pk2(v.z, v.w));
    }
    // stage encWT half: encWT[n][kk] = encW[half*128+kk][n] @us 8704, stride 136
    #pragma unroll
    for (int i = 0; i < 8; i++) {
      int idx = tid + 256 * i;             // 0..2047
      int row = idx >> 4, c4 = idx & 15;   // row = k within half (0..127)
      float4 v = ((const float4*)encW)[(half * 128 + row) * 16 + c4];
      u16* p = &ldsU[8704 + (4 * c4) * 136 + row];
      p[0]       = f2bf(v.x);
      p[136]     = f2bf(v.y);
      p[272]     = f2bf(v.z);
      p[408]     = f2bf(v.w);
    }
    if (half == 0) {
      // stage h_in: Dh[row][n] @us 22016, stride 72
      #pragma unroll
      for (int i = 0; i < 4; i++) {
        int idx = tid + 256 * i;           // 0..1023
        int row = idx >> 4, c4 = idx & 15;
        float4 v = hid4[(rowbase + row) * 16 + c4];
        *(uint2*)&ldsU[22016 + row * 72 + c4 * 4] = make_uint2(pk2(v.x, v.y), pk2(v.z, v.w));
      }
    }
    __syncthreads();
    #pragma unroll
    for (int ks = 0; ks < 4; ks++) {
      short8 a = *(const short8*)&ldsU[(M0 + l16) * 136 + ks * 32 + quad * 8];
      #pragma unroll
      for (int t = 0; t < 4; t++) {
        short8 b = *(const short8*)&ldsU[8704 + (16 * t + l16) * 136 + ks * 32 + quad * 8];
        ce[t] = MFMA16(a, b, ce[t]);
      }
    }
  }
  // epilogue: x bf16 -> Cx [64][72] @us 17408
  #pragma unroll
  for (int t = 0; t < 4; t++) {
    float bias = encb[16 * t + l16];
    #pragma unroll
    for (int r = 0; r < 4; r++) {
      float xv = fmaxf(ce[t][r] + bias, 0.f);
      ldsU[17408 + (M0 + quad * 4 + r) * 72 + 16 * t + l16] = f2bf(xv);
    }
  }
  __syncthreads();                         // x visible; enc frag reads retired

  // ================= GRU ====================================================
  // stage Wih [192][64] -> [192][72] bf16 @us 0
  #pragma unroll
  for (int i = 0; i < 12; i++) {
    int idx = tid + 256 * i;               // 0..3071
    int row = idx >> 4, c4 = idx & 15;
    float4 v = ((const float4*)Wih)[row * 16 + c4];
    *(uint2*)&ldsU[row * 72 + c4 * 4] = make_uint2(pk2(v.x, v.y), pk2(v.z, v.w));
  }
  __syncthreads();
  f32x4 gxr[12];
  #pragma unroll
  for (int t = 0; t < 12; t++) gxr[t] = (f32x4){0.f,0.f,0.f,0.f};
  #pragma unroll
  for (int ks = 0; ks < 2; ks++) {
    short8 a = *(const short8*)&ldsU[17408 + (M0 + l16) * 72 + ks * 32 + quad * 8];
    #pragma unroll
    for (int t = 0; t < 12; t++) {
      short8 b = *(const short8*)&ldsU[(16 * t + l16) * 72 + ks * 32 + quad * 8];
      gxr[t] = MFMA16(a, b, gxr[t]);
    }
  }
  __syncthreads();                         // retire Wih reads
  // stage Whh
  #pragma unroll
  for (int i = 0; i < 12; i++) {
    int idx = tid + 256 * i;
    int row = idx >> 4, c4 = idx & 15;
    float4 v = ((const float4*)Whh)[row * 16 + c4];
    *(uint2*)&ldsU[row * 72 + c4 * 4] = make_uint2(pk2(v.x, v.y), pk2(v.z, v.w));
  }
  __syncthreads();
  f32x4 ghr[12];
  #pragma unroll
  for (int t = 0; t < 12; t++) ghr[t] = (f32x4){0.f,0.f,0.f,0.f};
  #pragma unroll
  for (int ks = 0; ks < 2; ks++) {
    short8 a = *(const short8*)&ldsU[22016 + (M0 + l16) * 72 + ks * 32 + quad * 8];
    #pragma unroll
    for (int t = 0; t < 12; t++) {
      short8 b = *(const short8*)&ldsU[(16 * t + l16) * 72 + ks * 32 + quad * 8];
      ghr[t] = MFMA16(a, b, ghr[t]);
    }
  }
  __syncthreads();                         // retire Whh reads (before qkvT staging)

  // stage qkvT [96][72] @us 0 : rows 0-31 qW^T, 32-63 kW^T, 64-95 vW^T
  {
    const float* Ws[3] = {qW, kW, vW};
    #pragma unroll
    for (int mtx = 0; mtx < 3; mtx++) {
      const float4* W4 = (const float4*)Ws[mtx];
      #pragma unroll
      for (int i = 0; i < 2; i++) {
        int idx = tid + 256 * i;           // 0..511
        int k = idx >> 3, c4 = idx & 7;
        float4 v = W4[k * 8 + c4];
        u16* p = &ldsU[(mtx * 32 + 4 * c4) * 72 + k];
        p[0]   = f2bf(v.x);
        p[72]  = f2bf(v.y);
        p[144] = f2bf(v.z);
        p[216] = f2bf(v.w);
      }
    }
  }
  // GRU elementwise (registers + Dh + global h_out) — no R0 access
  {
    float* outH = out + (size_t)BTOT * NACT;
    #pragma unroll
    for (int u = 0; u < 4; u++) {
      int n = 16 * u + l16;
      float bri = bih[n],       brh = bhh[n];
      float bzi = bih[64 + n],  bzh = bhh[64 + n];
      float bni = bih[128 + n], bnh = bhh[128 + n];
      #pragma unroll
      for (int r = 0; r < 4; r++) {
        int m = M0 + quad * 4 + r;
        float rg = sigm((gxr[u][r]     + bri) + (ghr[u][r]     + brh));
        float zg = sigm((gxr[4+u][r]   + bzi) + (ghr[4+u][r]   + bzh));
        float nn = tanhp((gxr[8+u][r]  + bni) + rg * (ghr[8+u][r] + bnh));
        float hp = bf2f(ldsU[22016 + m * 72 + n]);
        float ho = (1.f - zg) * nn + zg * hp;
        outH[(rowbase + m) * H + n] = ho;
        ldsU[22016 + m * 72 + n] = f2bf(ho);
      }
    }
  }
  __syncthreads();                         // h_out + qkvT visible

  // ================= q,k,v GEMM =============================================
  f32x4 cq[6];
  #pragma unroll
  for (int t = 0; t < 6; t++) cq[t] = (f32x4){0.f,0.f,0.f,0.f};
  #pragma unroll
  for (int ks = 0; ks < 2; ks++) {
    short8 a = *(const short8*)&ldsU[22016 + (M0 + l16) * 72 + ks * 32 + quad * 8];
    #pragma unroll
    for (int t = 0; t < 6; t++) {
      short8 b = *(const short8*)&ldsU[(16 * t + l16) * 72 + ks * 32 + quad * 8];
      cq[t] = MFMA16(a, b, cq[t]);
    }
  }
  __syncthreads();                         // retire qkvT reads

  // write q,k,v fp32 to attn area [row][104 f32] @f32 0 ; stage decT @us 13312
  {
    const float qs = 0.17677669529663687f; // 1/sqrt(32)
    #pragma unroll
    for (int t = 0; t < 6; t++) {
      int col = 16 * t + l16;              // 0..95 : q 0-31, k 32-63, v 64-95
      float add = (t >= 4) ? vb[col - 64] : 0.f;
      #pragma unroll
      for (int r = 0; r < 4; r++) {
        float vv = cq[t][r] + add;
        if (t < 2) vv *= qs;
        if (t >= 4) vv = fmaxf(vv, 0.f);
        R0f[(M0 + quad * 4 + r) * 104 + col] = vv;
      }
    }
    // decT[n][k] = decW[k][n] (n<14), [16][104] bf16 @us 13312
    #pragma unroll
    for (int i = 0; i < 6; i++) {
      int idx = tid + 256 * i;             // 0..1535
      int k = idx >> 4, n = idx & 15;
      float val = (n < 14) ? decW[k * NACT + n] : 0.f;
      ldsU[13312 + n * 104 + k] = f2bf(val);
    }
  }
  __syncthreads();

  // ================= attention (VALU fp32, 4 lanes/row) =====================
  {
    const int r  = tid >> 2;               // row 0..63
    const int s4 = tid & 3;
    const int gb = r & ~7, ri = r & 7;
    const float* fq = &R0f[r * 104];
    float sc[2];
    #pragma unroll
    for (int jj = 0; jj < 2; jj++) {
      int j = s4 + 4 * jj;
      const float* fk = &R0f[(gb + j) * 104 + 32];
      float d = 0.f;
      #pragma unroll
      for (int a4 = 0; a4 < 32; a4 += 4) {
        float4 q4 = *(const float4*)&fq[a4];
        float4 k4 = *(const float4*)&fk[a4];
        d += q4.x*k4.x + q4.y*k4.y + q4.z*k4.z + q4.w*k4.w;
      }
      sc[jj] = (j == ri) ? -1e30f : d;
    }
    float m = fmaxf(sc[0], sc[1]);
    m = fmaxf(m, __shfl_xor(m, 1, 4));
    m = fmaxf(m, __shfl_xor(m, 2, 4));
    float p0 = (s4     == ri) ? 0.f : __expf(sc[0] - m);
    float p1 = (s4 + 4 == ri) ? 0.f : __expf(sc[1] - m);
    float sum = p0 + p1;
    sum += __shfl_xor(sum, 1, 4);
    sum += __shfl_xor(sum, 2, 4);
    float inv = 1.f / sum;
    R0f[r * 104 + 96 + s4]     = p0 * inv;
    R0f[r * 104 + 96 + s4 + 4] = p1 * inv;
    // xatt dims a = s4*8 .. s4*8+7  (within-wave LDS dependencies only)
    float xa[8] = {0,0,0,0,0,0,0,0};
    #pragma unroll
    for (int j = 0; j < 8; j++) {
      float aj = R0f[r * 104 + 96 + j];
      const float* fv = &R0f[(gb + j) * 104 + 64 + s4 * 8];
      #pragma unroll
      for (int u = 0; u < 8; u++) xa[u] += aj * fv[u];
    }
    *(uint4*)&ldsU[17408 + r * 72 + s4 * 8] =
        make_uint4(pk2(xa[0], xa[1]), pk2(xa[2], xa[3]),
                   pk2(xa[4], xa[5]), pk2(xa[6], xa[7]));
  }
  __syncthreads();                         // xatt visible

  // ================= dec GEMM: [h_out | xatt] @ decW + decb =================
  {
    f32x4 co = (f32x4){0.f,0.f,0.f,0.f};
    #pragma unroll
    for (int ks = 0; ks < 3; ks++) {
      short8 a;
      if (ks < 2) a = *(const short8*)&ldsU[22016 + (M0 + l16) * 72 + ks * 32 + quad * 8];
      else        a = *(const short8*)&ldsU[17408 + (M0 + l16) * 72 + quad * 8];
      short8 b = *(const short8*)&ldsU[13312 + l16 * 104 + ks * 32 + quad * 8];
      co = MFMA16(a, b, co);
    }
    if (l16 < NACT) {
      float bias = decb[l16];
      #pragma unroll
      for (int r = 0; r < 4; r++) {
        int m = M0 + quad * 4 + r;
        out[(rowbase + m) * NACT + l16] = co[r] + bias;
      }
    }
  }
}

extern "C" void kernel_launch(void* const* d_in, const int* in_sizes, int n_in,
                              void* d_out, int out_size, void* d_ws, size_t ws_size,
                              hipStream_t stream) {
  (void)in_sizes; (void)n_in; (void)d_ws; (void)ws_size; (void)out_size;
  const float* obs  = (const float*)d_in[0];
  const float* hid  = (const float*)d_in[1];
  const float* encW = (const float*)d_in[2];
  const float* encb = (const float*)d_in[3];
  const float* Wih  = (const float*)d_in[4];
  const float* Whh  = (const float*)d_in[5];
  const float* bih  = (const float*)d_in[6];
  const float* bhh  = (const float*)d_in[7];
  const float* qW   = (const float*)d_in[8];
  const float* kW   = (const float*)d_in[9];
  const float* vW   = (const float*)d_in[10];
  const float* vb   = (const float*)d_in[11];
  const float* decW = (const float*)d_in[12];
  const float* decb = (const float*)d_in[13];
  float* out = (float*)d_out;

  commslave_mfma<<<BTOT / MBLK, 256, 0, stream>>>(
      obs, hid, encW, encb, Wih, Whh, bih, bhh, qW, kW, vW, vb, decW, decb, out);
}